// Round 1
// baseline (8155.781 us; speedup 1.0000x reference)
//
#include <hip/hip_runtime.h>
#include <hip/hip_bf16.h>

// GraphEncoder: pre-Linear(3->32)+tanh -> GATConv(32->32, skeleton) -> LSTM(768->768, L=256)
// Inputs/outputs fp32. Compute: bf16 MFMA operands, fp32 accum/state.
//
// R4: persistent LSTM v2 — 48 WGs x 512 threads, each WG owns 16 units (64 gate
// cols, Whh slice 96 KB in LDS) x all 128 batch rows. G prefetched one step
// ahead (registers), counted vmcnt(5) retires only the h store before barrier
// arrival, out stores full-line coalesced, fast sigmoid/tanh via v_exp/v_rcp.
//
// ws layout (bytes):
//   0          Xb      bf16  50331648
//   50331648   WihC    bf16   4718592
//   55050240   WhhC    bf16   4718592
//   59768832   cs      fp32    393216   (legacy path only)
//   60162048   h0      bf16    196608
//   60358656   h1      bf16    196608
//   60555264   smallC  fp32     32768
//   60588032   bar     int       8192   (group counters [t*8+g], epoch at [2040])
//   60596224   G       fp32 402653184   (layout [t][128][3072])

#define NB 128
#define LSEQ 256
#define LH 768
#define BGR 32768
#define NWG 96     // legacy path
#define PWG2 48    // persistent path v2

typedef __attribute__((ext_vector_type(8))) short short8;
typedef __attribute__((ext_vector_type(4))) float floatx4;
typedef __attribute__((ext_vector_type(4))) unsigned int uint4v;
typedef __attribute__((ext_vector_type(2))) unsigned int uint2v;

union frag16 { uint4v u; short8 s; };
union bfbits { __hip_bfloat16 h; unsigned short s; };
union uf4 { uint4v u; float f[4]; };

// fast sigmoid/tanh: v_exp_f32 (2^x) + v_rcp_f32, ~1 ulp — far below bf16 noise
__device__ __forceinline__ float fsig(float x) {
    return __builtin_amdgcn_rcpf(1.f + __builtin_amdgcn_exp2f(-1.44269504f * x));
}
__device__ __forceinline__ float ftanhf(float x) {
    return 1.f - 2.f * __builtin_amdgcn_rcpf(1.f + __builtin_amdgcn_exp2f(2.88539008f * x));
}

// 8 MALL-coherent 16B loads at base + {0..448}
__device__ __forceinline__ void issue8(uint4v* b, const char* base) {
    asm volatile("global_load_dwordx4 %0, %1, off sc0 sc1"            : "=v"(b[0]) : "v"(base));
    asm volatile("global_load_dwordx4 %0, %1, off offset:64 sc0 sc1"  : "=v"(b[1]) : "v"(base));
    asm volatile("global_load_dwordx4 %0, %1, off offset:128 sc0 sc1" : "=v"(b[2]) : "v"(base));
    asm volatile("global_load_dwordx4 %0, %1, off offset:192 sc0 sc1" : "=v"(b[3]) : "v"(base));
    asm volatile("global_load_dwordx4 %0, %1, off offset:256 sc0 sc1" : "=v"(b[4]) : "v"(base));
    asm volatile("global_load_dwordx4 %0, %1, off offset:320 sc0 sc1" : "=v"(b[5]) : "v"(base));
    asm volatile("global_load_dwordx4 %0, %1, off offset:384 sc0 sc1" : "=v"(b[6]) : "v"(base));
    asm volatile("global_load_dwordx4 %0, %1, off offset:448 sc0 sc1" : "=v"(b[7]) : "v"(base));
}
// waitcnt with register ties so the compiler cannot hoist consumers above it
__device__ __forceinline__ void wait16_touch(uint4v* a, uint4v* b) {
    asm volatile("s_waitcnt vmcnt(16)"
        : "+v"(a[0]), "+v"(a[1]), "+v"(a[2]), "+v"(a[3]),
          "+v"(a[4]), "+v"(a[5]), "+v"(a[6]), "+v"(a[7]),
          "+v"(b[0]), "+v"(b[1]), "+v"(b[2]), "+v"(b[3]),
          "+v"(b[4]), "+v"(b[5]), "+v"(b[6]), "+v"(b[7]) :: "memory");
}
__device__ __forceinline__ void wait0_touch(uint4v* a, uint4v* b,
                                            uint4v* g0, uint4v* g1, uint4v* g2, uint4v* g3) {
    asm volatile("s_waitcnt vmcnt(0)"
        : "+v"(a[0]), "+v"(a[1]), "+v"(a[2]), "+v"(a[3]),
          "+v"(a[4]), "+v"(a[5]), "+v"(a[6]), "+v"(a[7]),
          "+v"(b[0]), "+v"(b[1]), "+v"(b[2]), "+v"(b[3]),
          "+v"(b[4]), "+v"(b[5]), "+v"(b[6]), "+v"(b[7]),
          "+v"(*g0), "+v"(*g1), "+v"(*g2), "+v"(*g3) :: "memory");
}

// ---------------- Canonicalize weights (fp32 inputs) ----------------
// smallC: W_pre@0(96) b_pre@96(32) W_gat@128(1024) att_src@1152(32)
//         att_dst@1184(32) b_gat@1216(32) b_ih@1248(3072) b_hh@4320(3072)
__global__ __launch_bounds__(256) void convert_kernel(
    const float* W_pre, const float* b_pre, const float* W_gat,
    const float* att_src, const float* att_dst, const float* b_gat,
    const float* W_ih, const float* W_hh, const float* b_ih, const float* b_hh,
    __hip_bfloat16* __restrict__ WihC, __hip_bfloat16* __restrict__ WhhC,
    float* __restrict__ smallC)
{
    long i = (long)blockIdx.x * 256 + threadIdx.x;
    if (i < 2359296) { WihC[i] = __float2bfloat16(W_ih[i]); return; }
    i -= 2359296;
    if (i < 2359296) { WhhC[i] = __float2bfloat16(W_hh[i]); return; }
    i -= 2359296;
    if (i < 96)   { smallC[0 + i]    = W_pre[i];   return; }  i -= 96;
    if (i < 32)   { smallC[96 + i]   = b_pre[i];   return; }  i -= 32;
    if (i < 1024) { smallC[128 + i]  = W_gat[i];   return; }  i -= 1024;
    if (i < 32)   { smallC[1152 + i] = att_src[i]; return; }  i -= 32;
    if (i < 32)   { smallC[1184 + i] = att_dst[i]; return; }  i -= 32;
    if (i < 32)   { smallC[1216 + i] = b_gat[i];   return; }  i -= 32;
    if (i < 3072) { smallC[1248 + i] = b_ih[i];    return; }  i -= 3072;
    if (i < 3072) { smallC[4320 + i] = b_hh[i];    return; }
}

// ---------------- Kernel A: pre + GAT -> Xb (bf16) ----------------
__global__ __launch_bounds__(256) void gat_pre_kernel(
    const float* __restrict__ src,           // [32768][72]
    const float* __restrict__ smallC,
    __hip_bfloat16* __restrict__ Xb)         // [32768][768]
{
    __shared__ float wpre[96];
    __shared__ float bpre[32];
    __shared__ float wgat[1024];
    __shared__ float asrc[32];
    __shared__ float adst[32];
    __shared__ float bgat[32];
    __shared__ float xl[8][72];
    __shared__ float hl[8][24][32];
    __shared__ float xpl[8][24][32];
    __shared__ float asl[8][24];
    __shared__ float adl[8][24];

    const int tid = threadIdx.x;
    for (int i = tid; i < 96; i += 256)   wpre[i] = smallC[i];
    for (int i = tid; i < 1024; i += 256) wgat[i] = smallC[128 + i];
    if (tid < 32) {
        bpre[tid] = smallC[96 + tid];
        asrc[tid] = smallC[1152 + tid];
        adst[tid] = smallC[1184 + tid];
        bgat[tid] = smallC[1216 + tid];
    }

    const int g = tid >> 5;
    const int k = tid & 31;
    const long gb = (long)blockIdx.x * 8 + g;   // graph id = n*256 + t

    for (int i = k; i < 72; i += 32)
        xl[g][i] = src[gb * 72 + i];
    __syncthreads();

    #pragma unroll
    for (int j = 0; j < 24; ++j) {
        float v = xl[g][j*3+0] * wpre[0*32+k]
                + xl[g][j*3+1] * wpre[1*32+k]
                + xl[g][j*3+2] * wpre[2*32+k] + bpre[k];
        hl[g][j][k] = tanhf(v);
    }
    __syncthreads();

    #pragma unroll
    for (int j = 0; j < 24; ++j) {
        float v = 0.f;
        #pragma unroll
        for (int m = 0; m < 32; ++m) v += hl[g][j][m] * wgat[m*32 + k];
        xpl[g][j][k] = v;
    }
    __syncthreads();

    if (k < 24) {
        float vs = 0.f, vd = 0.f;
        #pragma unroll
        for (int m = 0; m < 32; ++m) {
            float x = xpl[g][k][m];
            vs += x * asrc[m];
            vd += x * adst[m];
        }
        asl[g][k] = vs;
        adl[g][k] = vd;
    }
    __syncthreads();

    const int par[24] = {-1,0,0,0,1,2,3,4,5,6,7,8,9,9,9,12,13,14,16,17,18,19,20,21};
    #pragma unroll
    for (int j = 0; j < 24; ++j) {
        int p = par[j];
        float o;
        if (p < 0) {
            o = xpl[g][j][k] + bgat[k];
        } else {
            float es = adl[g][j] + asl[g][j];
            float ep = adl[g][j] + asl[g][p];
            es = es > 0.f ? es : 0.2f * es;
            ep = ep > 0.f ? ep : 0.2f * ep;
            float mx = fmaxf(es, ep);
            float wse = expf(es - mx), wpe = expf(ep - mx);
            float inv = 1.f / (wse + wpe);
            o = (wse * xpl[g][j][k] + wpe * xpl[g][p][k]) * inv + bgat[k];
        }
        Xb[gb * 768 + j * 32 + k] = __float2bfloat16(o);
    }
}

// ---------------- gates_in: G = X @ Wih^T + (b_ih+b_hh), 128x128 tiles ----------------
// grid (256, 24): bx = M-block (rows m*256+t of Xb), by = N-block (wrows).
// G layout [t][128][3072].
__global__ __launch_bounds__(256) void gates_in_kernel(
    const __hip_bfloat16* __restrict__ Xb,   // [32768][768]
    const __hip_bfloat16* __restrict__ Wih,  // [3072][768]
    const float* __restrict__ smallC,
    float* __restrict__ Gf)
{
    const int tid = threadIdx.x;
    const int w = tid >> 6, L = tid & 63;
    const int rh2 = w >> 1, ch2 = w & 1;
    const int q = L >> 4, col16 = L & 15;
    const int R0 = blockIdx.x * 128;
    const int N0 = blockIdx.y * 128;

    const short8* ap[4];
    const short8* bp[4];
    #pragma unroll
    for (int i = 0; i < 4; ++i) {
        ap[i] = (const short8*)(Xb + (size_t)(R0 + 64*rh2 + 16*i + col16) * 768 + q*8);
        bp[i] = (const short8*)(Wih + (size_t)(N0 + 64*ch2 + 16*i + col16) * 768 + q*8);
    }

    floatx4 acc[4][4] = {};
    for (int kk = 0; kk < 24; ++kk) {
        short8 a[4], b[4];
        #pragma unroll
        for (int i = 0; i < 4; ++i) { a[i] = ap[i][kk*4]; b[i] = bp[i][kk*4]; }
        #pragma unroll
        for (int rt = 0; rt < 4; ++rt)
            #pragma unroll
            for (int bt = 0; bt < 4; ++bt)
                acc[rt][bt] = __builtin_amdgcn_mfma_f32_16x16x32_bf16(a[rt], b[bt], acc[rt][bt], 0, 0, 0);
    }

    #pragma unroll
    for (int bt = 0; bt < 4; ++bt) {
        int wrow = N0 + 64*ch2 + 16*bt + col16;
        float bias = smallC[1248 + wrow] + smallC[4320 + wrow];
        #pragma unroll
        for (int rt = 0; rt < 4; ++rt) {
            #pragma unroll
            for (int r = 0; r < 4; ++r) {
                int m_abs = R0 + 64*rh2 + 16*rt + q*4 + r;   // = m*256 + t
                int mm = m_abs >> 8, tt = m_abs & 255;
                size_t idx = ((size_t)tt * 128 + mm) * 3072 + wrow;
                Gf[idx] = acc[rt][bt][r] + bias;
            }
        }
    }
}

// ---------------- Persistent LSTM v2: 48 WGs x 512 threads ----------------
// WG cg owns units cg*16..+15 (64 gate cols; Whh slice 96 KB in LDS) for ALL
// 128 batch rows. 8 waves = 4 row-waves (32 rows) x 2 col-waves (32 cols).
// h via sc0/sc1 (MALL-coherent). Two-level relaxed-atomic barrier: 8 groups x 6.
// G prefetched one step ahead into regs; counted vmcnt(5) retires only h store.
__global__ __launch_bounds__(512) void lstm_persist2_kernel(
    const float* __restrict__ G,              // [t][128][3072] fp32
    const __hip_bfloat16* __restrict__ Whh,   // [3072][768]
    __hip_bfloat16* __restrict__ h0g,         // ping-pong h (h0 zeroed)
    __hip_bfloat16* __restrict__ h1g,
    float* __restrict__ out,
    int* __restrict__ bar)
{
    __shared__ short8 whhs[6144];             // [kk 0..23][c 0..63][q 0..3], 96 KB
    __shared__ float gl[128 * 66];            // gate staging, 33 KB

    const int tid = threadIdx.x;
    const int w = tid >> 6;                   // wave 0..7
    const int L = tid & 63;
    const int q = L >> 4;
    const int col16 = L & 15;
    const int rw = w >> 1;                    // row-wave: rows 32rw..+31
    const int cwv = w & 1;                    // col-wave: cols 32cwv..+31
    const int cg = blockIdx.x;                // 0..47

    // ---- stage Whh slice into LDS (once): whhs[f], f=(kk<<8)|(c<<2)|q ----
    for (int b = 0; b < 12; ++b) {
        int f = tid + 512 * b;
        int kk = f >> 8, c = (f >> 2) & 63, qq = f & 3;
        int wrow = 768 * (c >> 4) + cg * 16 + (c & 15);
        whhs[f] = *(const short8*)(Whh + (size_t)wrow * 768 + kk * 32 + qq * 8);
    }
    __syncthreads();

    // epilogue assignment: thread -> (row m_ep, 4 consecutive units u4..u4+3)
    const int m_ep = tid >> 2;                // 0..127
    const int u4 = (tid & 3) * 4;             // 0,4,8,12 (local unit)
    const int ug = cg * 16 + u4;              // global unit base
    const int bidx = cwv * 128 + col16 * 4 + q;
    const long rowoff0 = ((long)(32 * rw + col16) * 768 + q * 8) * 2;
    const long rowoff1 = rowoff0 + 16 * 1536;
    float creg[4] = {0.f, 0.f, 0.f, 0.f};

    // prefetch G[0]
    uint4v gp0, gp1, gp2, gp3;
    {
        const char* gb = (const char*)(G + (size_t)m_ep * 3072 + ug);
        const char* gb2 = gb + 6144;
        asm volatile("global_load_dwordx4 %0, %1, off"             : "=v"(gp0) : "v"(gb));
        asm volatile("global_load_dwordx4 %0, %1, off offset:3072" : "=v"(gp1) : "v"(gb));
        asm volatile("global_load_dwordx4 %0, %1, off"             : "=v"(gp2) : "v"(gb2));
        asm volatile("global_load_dwordx4 %0, %1, off offset:3072" : "=v"(gp3) : "v"(gb2));
    }

    for (int t = 0; t < LSEQ; ++t) {
        const char* hrc = (const char*)((t & 1) ? h1g : h0g);
        __hip_bfloat16* hw = (t & 1) ? h0g : h1g;
        const char* hb0 = hrc + rowoff0;
        const char* hb1 = hrc + rowoff1;

        uint4v A0[8], B0[8], A1[8], B1[8];
        floatx4 acc00 = {}, acc01 = {}, acc10 = {}, acc11 = {};

        // phase-pipelined h loads (rows from MALL) against MFMA on LDS Whh
        issue8(A0, hb0);
        issue8(B0, hb1);
        issue8(A1, hb0 + 512);
        issue8(B1, hb1 + 512);
        wait16_touch(A0, B0);
        #pragma unroll
        for (int j = 0; j < 8; ++j) {
            frag16 fa, fb; fa.u = A0[j]; fb.u = B0[j];
            short8 bv0 = whhs[j * 256 + bidx];
            short8 bv1 = whhs[j * 256 + bidx + 64];
            acc00 = __builtin_amdgcn_mfma_f32_16x16x32_bf16(fa.s, bv0, acc00, 0, 0, 0);
            acc01 = __builtin_amdgcn_mfma_f32_16x16x32_bf16(fa.s, bv1, acc01, 0, 0, 0);
            acc10 = __builtin_amdgcn_mfma_f32_16x16x32_bf16(fb.s, bv0, acc10, 0, 0, 0);
            acc11 = __builtin_amdgcn_mfma_f32_16x16x32_bf16(fb.s, bv1, acc11, 0, 0, 0);
        }
        issue8(A0, hb0 + 1024);
        issue8(B0, hb1 + 1024);
        wait16_touch(A1, B1);
        #pragma unroll
        for (int j = 0; j < 8; ++j) {
            frag16 fa, fb; fa.u = A1[j]; fb.u = B1[j];
            short8 bv0 = whhs[(8 + j) * 256 + bidx];
            short8 bv1 = whhs[(8 + j) * 256 + bidx + 64];
            acc00 = __builtin_amdgcn_mfma_f32_16x16x32_bf16(fa.s, bv0, acc00, 0, 0, 0);
            acc01 = __builtin_amdgcn_mfma_f32_16x16x32_bf16(fa.s, bv1, acc01, 0, 0, 0);
            acc10 = __builtin_amdgcn_mfma_f32_16x16x32_bf16(fb.s, bv0, acc10, 0, 0, 0);
            acc11 = __builtin_amdgcn_mfma_f32_16x16x32_bf16(fb.s, bv1, acc11, 0, 0, 0);
        }
        wait0_touch(A0, B0, &gp0, &gp1, &gp2, &gp3);   // also retires G prefetch
        #pragma unroll
        for (int j = 0; j < 8; ++j) {
            frag16 fa, fb; fa.u = A0[j]; fb.u = B0[j];
            short8 bv0 = whhs[(16 + j) * 256 + bidx];
            short8 bv1 = whhs[(16 + j) * 256 + bidx + 64];
            acc00 = __builtin_amdgcn_mfma_f32_16x16x32_bf16(fa.s, bv0, acc00, 0, 0, 0);
            acc01 = __builtin_amdgcn_mfma_f32_16x16x32_bf16(fa.s, bv1, acc01, 0, 0, 0);
            acc10 = __builtin_amdgcn_mfma_f32_16x16x32_bf16(fb.s, bv0, acc10, 0, 0, 0);
            acc11 = __builtin_amdgcn_mfma_f32_16x16x32_bf16(fb.s, bv1, acc11, 0, 0, 0);
        }

        // ---- D -> gl: row = 32rw + 16rt + 4q + r, col = 32cwv + 16ct + col16 ----
        #pragma unroll
        for (int r = 0; r < 4; ++r) {
            int row0 = 32 * rw + 4 * q + r;
            gl[row0 * 66 + 32 * cwv + col16]             = acc00[r];
            gl[row0 * 66 + 32 * cwv + 16 + col16]        = acc01[r];
            gl[(row0 + 16) * 66 + 32 * cwv + col16]      = acc10[r];
            gl[(row0 + 16) * 66 + 32 * cwv + 16 + col16] = acc11[r];
        }
        __syncthreads();

        // ---- elementwise LSTM update: 4 units per thread ----
        uf4 gI, gF, gG, gO;
        gI.u = gp0; gF.u = gp1; gG.u = gp2; gO.u = gp3;
        const float* glr = gl + m_ep * 66 + u4;
        float hv[4];
        #pragma unroll
        for (int k2 = 0; k2 < 4; ++k2) {
            float ig = gI.f[k2] + glr[0 + k2];
            float fg = gF.f[k2] + glr[16 + k2];
            float gg = gG.f[k2] + glr[32 + k2];
            float og = gO.f[k2] + glr[48 + k2];
            float si = fsig(ig), sf = fsig(fg), so = fsig(og);
            float cn = sf * creg[k2] + si * ftanhf(gg);
            hv[k2] = so * ftanhf(cn);
            creg[k2] = cn;
        }

        bfbits p0, p1, p2, p3;
        p0.h = __float2bfloat16(hv[0]); p1.h = __float2bfloat16(hv[1]);
        p2.h = __float2bfloat16(hv[2]); p3.h = __float2bfloat16(hv[3]);
        uint2v hp;
        hp.x = (unsigned)p0.s | ((unsigned)p1.s << 16);
        hp.y = (unsigned)p2.s | ((unsigned)p3.s << 16);
        char* ha = (char*)hw + (size_t)(m_ep * 768 + ug) * 2;
        floatx4 ov; ov[0] = hv[0]; ov[1] = hv[1]; ov[2] = hv[2]; ov[3] = hv[3];
        float* oa = out + ((size_t)m_ep * 256 + t) * 768 + ug;

        if (t < LSEQ - 1) {
            // h store (must drain before arrival), then G[t+1] prefetch + out
            // store issued BEHIND it: vmcnt(5) retires exactly the h store.
            asm volatile("global_store_dwordx2 %0, %1, off sc0 sc1" :: "v"(ha), "v"(hp) : "memory");
            const char* gb = (const char*)(G + ((size_t)(t + 1) * 128 + m_ep) * 3072 + ug);
            const char* gb2 = gb + 6144;
            asm volatile("global_load_dwordx4 %0, %1, off"             : "=v"(gp0) : "v"(gb));
            asm volatile("global_load_dwordx4 %0, %1, off offset:3072" : "=v"(gp1) : "v"(gb));
            asm volatile("global_load_dwordx4 %0, %1, off"             : "=v"(gp2) : "v"(gb2));
            asm volatile("global_load_dwordx4 %0, %1, off offset:3072" : "=v"(gp3) : "v"(gb2));
            asm volatile("global_store_dwordx4 %0, %1, off" :: "v"(oa), "v"(ov) : "memory");
            asm volatile("s_waitcnt vmcnt(5)" ::: "memory");
            __syncthreads();
            if (tid == 0) {
                int g = blockIdx.x & 7;
                int prev = __hip_atomic_fetch_add(&bar[t * 8 + g], 1,
                                                  __ATOMIC_RELAXED, __HIP_MEMORY_SCOPE_AGENT);
                bool rel = false;
                if ((prev & 255) == 5) {                   // 6th of this group
                    int pr = __hip_atomic_fetch_add(&bar[t * 8], 256,
                                                    __ATOMIC_RELAXED, __HIP_MEMORY_SCOPE_AGENT);
                    if ((pr >> 8) == 7) {                  // 8th group
                        __hip_atomic_store(&bar[2040], t + 1,
                                           __ATOMIC_RELAXED, __HIP_MEMORY_SCOPE_AGENT);
                        rel = true;
                    }
                }
                if (!rel) {
                    while (__hip_atomic_load(&bar[2040], __ATOMIC_RELAXED,
                                             __HIP_MEMORY_SCOPE_AGENT) < t + 1)
                        __builtin_amdgcn_s_sleep(2);
                }
            }
            __syncthreads();
        } else {
            *(floatx4*)oa = ov;
            const size_t base = (size_t)NB * LSEQ * LH;
            const size_t ci = (size_t)m_ep * 768 + ug;
            floatx4 cv; cv[0] = creg[0]; cv[1] = creg[1]; cv[2] = creg[2]; cv[3] = creg[3];
            *(floatx4*)(out + base + ci) = ov;
            *(floatx4*)(out + base + (size_t)NB * LH + ci) = cv;
        }
    }
}

// ---------------- Legacy per-step path (ws fallback, proven) ----------------
__global__ __launch_bounds__(256) void lstm_step_kernel(
    const __hip_bfloat16* __restrict__ Xb,
    const __hip_bfloat16* __restrict__ Wih,
    const __hip_bfloat16* __restrict__ Whh,
    const float* __restrict__ smallC,
    float* __restrict__ cst,
    const __hip_bfloat16* __restrict__ hr,
    __hip_bfloat16* __restrict__ hw,
    float* __restrict__ out,
    int t)
{
    __shared__ float gls[128 * 33];
    const int tid = threadIdx.x;
    const int w = tid >> 6;
    const int L = tid & 63;
    const int rh = w >> 1;
    const int ct = w & 1;
    const int q = L >> 4;
    const int col16 = L & 15;
    const int c_local = 16 * ct + col16;
    const int gate = c_local >> 3;
    const int uu = c_local & 7;
    const int u = 8 * blockIdx.x + uu;
    const int wrow = 768 * gate + u;

    const short8* bp_i = (const short8*)(Wih + (long)wrow * 768 + q * 8);
    const short8* bp_h = (const short8*)(Whh + (long)wrow * 768 + q * 8);
    const short8* ap_x[4];
    const short8* ap_h[4];
    #pragma unroll
    for (int rt = 0; rt < 4; ++rt) {
        int m = 64 * rh + 16 * rt + col16;
        ap_x[rt] = (const short8*)(Xb + ((long)m * LSEQ + t) * 768 + q * 8);
        ap_h[rt] = (const short8*)(hr + (long)m * 768 + q * 8);
    }
    floatx4 acc[4] = {};
    for (int kk = 0; kk < 768; kk += 32) {
        short8 bv = bp_i[kk >> 3];
        #pragma unroll
        for (int rt = 0; rt < 4; ++rt)
            acc[rt] = __builtin_amdgcn_mfma_f32_16x16x32_bf16(ap_x[rt][kk >> 3], bv, acc[rt], 0, 0, 0);
    }
    for (int kk = 0; kk < 768; kk += 32) {
        short8 bv = bp_h[kk >> 3];
        #pragma unroll
        for (int rt = 0; rt < 4; ++rt)
            acc[rt] = __builtin_amdgcn_mfma_f32_16x16x32_bf16(ap_h[rt][kk >> 3], bv, acc[rt], 0, 0, 0);
    }
    float bias = smallC[1248 + wrow] + smallC[4320 + wrow];
    #pragma unroll
    for (int rt = 0; rt < 4; ++rt)
        #pragma unroll
        for (int r = 0; r < 4; ++r) {
            int m = 64 * rh + 16 * rt + q * 4 + r;
            gls[m * 33 + c_local] = acc[rt][r] + bias;
        }
    __syncthreads();
    for (int item = tid; item < 1024; item += 256) {
        int m = item >> 3;
        int u2l = item & 7;
        float ig = gls[m * 33 + 0  + u2l];
        float fg = gls[m * 33 + 8  + u2l];
        float gg = gls[m * 33 + 16 + u2l];
        float og = gls[m * 33 + 24 + u2l];
        int u2 = 8 * blockIdx.x + u2l;
        int ci = m * 768 + u2;
        float co = cst[ci];
        float si = 1.f / (1.f + expf(-ig));
        float sf = 1.f / (1.f + expf(-fg));
        float so = 1.f / (1.f + expf(-og));
        float cn = sf * co + si * tanhf(gg);
        float h = so * tanhf(cn);
        cst[ci] = cn;
        hw[ci] = __float2bfloat16(h);
        out[((long)m * LSEQ + t) * 768 + u2] = h;
    }
}

__global__ __launch_bounds__(256) void finalize_kernel(
    const __hip_bfloat16* __restrict__ hfin,
    const float* __restrict__ cst,
    float* __restrict__ out)
{
    int i = blockIdx.x * 256 + threadIdx.x;
    const long base = (long)NB * LSEQ * LH;
    out[base + i] = __bfloat162float(hfin[i]);
    out[base + NB * LH + i] = cst[i];
}

extern "C" void kernel_launch(void* const* d_in, const int* in_sizes, int n_in,
                              void* d_out, int out_size, void* d_ws, size_t ws_size,
                              hipStream_t stream) {
    const float* src     = (const float*)d_in[0];
    const float* W_pre   = (const float*)d_in[1];
    const float* b_pre   = (const float*)d_in[2];
    const float* W_gat   = (const float*)d_in[3];
    const float* att_src = (const float*)d_in[4];
    const float* att_dst = (const float*)d_in[5];
    const float* b_gat   = (const float*)d_in[6];
    const float* W_ih    = (const float*)d_in[7];
    const float* W_hh    = (const float*)d_in[8];
    const float* b_ih    = (const float*)d_in[9];
    const float* b_hh    = (const float*)d_in[10];

    float* out = (float*)d_out;
    char* ws = (char*)d_ws;

    __hip_bfloat16* Xb     = (__hip_bfloat16*)(ws);
    __hip_bfloat16* WihC   = (__hip_bfloat16*)(ws + 50331648);
    __hip_bfloat16* WhhC   = (__hip_bfloat16*)(ws + 55050240);
    float*          cs     = (float*)         (ws + 59768832);
    __hip_bfloat16* h0     = (__hip_bfloat16*)(ws + 60162048);
    __hip_bfloat16* h1     = (__hip_bfloat16*)(ws + 60358656);
    float*          smallC = (float*)         (ws + 60555264);
    int*            bar    = (int*)           (ws + 60588032);
    float*          Gin    = (float*)         (ws + 60596224);

    const size_t need_f32 = 60596224 + (size_t)BGR * 3072 * 4;   // ~463 MB
    const int use_persist = (ws_size >= need_f32);

    hipMemsetAsync(h0, 0, NB * LH * sizeof(__hip_bfloat16), stream);

    const long conv_total = 2359296L * 2 + 7392;
    convert_kernel<<<(int)((conv_total + 255) / 256), 256, 0, stream>>>(
        W_pre, b_pre, W_gat, att_src, att_dst, b_gat,
        W_ih, W_hh, b_ih, b_hh, WihC, WhhC, smallC);

    gat_pre_kernel<<<BGR / 8, 256, 0, stream>>>(src, smallC, Xb);

    if (use_persist) {
        hipMemsetAsync(bar, 0, 8192, stream);
        dim3 ggrid(256, 24);
        gates_in_kernel<<<ggrid, 256, 0, stream>>>(Xb, WihC, smallC, Gin);
        lstm_persist2_kernel<<<PWG2, 512, 0, stream>>>(Gin, WhhC, h0, h1, out, bar);
    } else {
        hipMemsetAsync(cs, 0, NB * LH * sizeof(float), stream);
        __hip_bfloat16* hp[2] = {h0, h1};
        for (int t = 0; t < LSEQ; ++t) {
            lstm_step_kernel<<<NWG, 256, 0, stream>>>(Xb, WihC, WhhC, smallC,
                                                      cs, hp[t & 1], hp[(t + 1) & 1],
                                                      out, t);
        }
        finalize_kernel<<<NB * LH / 256, 256, 0, stream>>>(h0, cs, out);
    }
}